// Round 1
// baseline (486.373 us; speedup 1.0000x reference)
//
#include <hip/hip_runtime.h>

// Problem constants (match reference setup_inputs)
constexpr int N_NODES = 50000;
constexpr int N_EDGES = 25000;
constexpr int C = 256;   // IN == OUT == 256 channels
constexpr int L = 32;    // incidence list width

// ---------------------------------------------------------------------------
// gather_avg: dst[row,:] = (1/cnt) * sum_{l: idx[row,l]>0} src[idx[row,l],:]
// (cnt==0 edge case: uniform 1/L over all slots == src[0,:])
// One wave (64 lanes) per output row; each lane owns 4 channels via float4.
// ---------------------------------------------------------------------------
__global__ __launch_bounds__(256) void gather_avg_kernel(
    const float* __restrict__ src, const int* __restrict__ idx,
    float* __restrict__ dst, int nrows)
{
    const int row  = blockIdx.x * 4 + (threadIdx.x >> 6);
    const int lane = threadIdx.x & 63;
    if (row >= nrows) return;

    const int* ir = idx + (size_t)row * L;
    int ids[L];
    int cnt = 0;
#pragma unroll
    for (int l = 0; l < L; ++l) { ids[l] = ir[l]; cnt += (ids[l] > 0) ? 1 : 0; }
    const bool all = (cnt == 0);
    const float w = all ? (1.0f / (float)L) : (1.0f / (float)cnt);

    float4 acc = make_float4(0.f, 0.f, 0.f, 0.f);
#pragma unroll
    for (int l = 0; l < L; ++l) {
        if (all || ids[l] > 0) {
            const float4 v = *reinterpret_cast<const float4*>(
                src + (size_t)ids[l] * C + lane * 4);
            acc.x += v.x; acc.y += v.y; acc.z += v.z; acc.w += v.w;
        }
    }
    float4 o = make_float4(acc.x * w, acc.y * w, acc.z * w, acc.w * w);
    *reinterpret_cast<float4*>(dst + (size_t)row * C + lane * 4) = o;
}

// ---------------------------------------------------------------------------
// gemm256: Cmat[M,256] = A[M,256] @ B[256,256], optional fused ReLU.
// 64x64 block tile, BK=32, 256 threads, 4x4 register tile per thread.
// As stored transposed [k][m] with +4 pad (keeps 16B alignment, breaks the
// 8-way bank conflict on the transposed store down to 4-way).
// ---------------------------------------------------------------------------
template<bool RELU>
__global__ __launch_bounds__(256) void gemm256_kernel(
    const float* __restrict__ A, const float* __restrict__ B,
    float* __restrict__ Cmat, int M)
{
    constexpr int BM = 64, BN = 64, BK = 32, PAD = 4;
    __shared__ __align__(16) float As[BK][BM + PAD];
    __shared__ __align__(16) float Bs[BK][BN];

    const int tid = threadIdx.x;
    const int bm = blockIdx.x * BM;
    const int bn = blockIdx.y * BN;

    // A-load mapping: 32 rows/pass, thread -> (row = tid/8, k-float4 = tid%8)
    const int arow = tid >> 3;          // 0..31
    const int ak4  = (tid & 7) * 4;     // 0,4,...,28
    // B-load mapping: 16 rows/pass, thread -> (k = tid/16, n-float4 = tid%16)
    const int bk   = tid >> 4;          // 0..15
    const int bn4  = (tid & 15) * 4;    // 0..60
    // compute mapping: 4 rows x 4 cols per thread
    const int tm = (tid >> 4) * 4;      // 0..60
    const int tn = (tid & 15) * 4;      // 0..60

    float acc[4][4] = {};

    for (int k0 = 0; k0 < C; k0 += BK) {
#pragma unroll
        for (int p = 0; p < 2; ++p) {
            const int m = arow + p * 32;
            int gm = bm + m; if (gm > M - 1) gm = M - 1;   // clamp tail reads
            const float4 v = *reinterpret_cast<const float4*>(
                A + (size_t)gm * C + k0 + ak4);
            As[ak4 + 0][m] = v.x; As[ak4 + 1][m] = v.y;
            As[ak4 + 2][m] = v.z; As[ak4 + 3][m] = v.w;
        }
#pragma unroll
        for (int p = 0; p < 2; ++p) {
            const int k = bk + p * 16;
            const float4 v = *reinterpret_cast<const float4*>(
                B + (size_t)(k0 + k) * C + bn + bn4);
            *reinterpret_cast<float4*>(&Bs[k][bn4]) = v;
        }
        __syncthreads();
#pragma unroll
        for (int k = 0; k < BK; ++k) {
            const float4 a = *reinterpret_cast<const float4*>(&As[k][tm]);
            const float4 b = *reinterpret_cast<const float4*>(&Bs[k][tn]);
            const float av[4] = {a.x, a.y, a.z, a.w};
            const float bv[4] = {b.x, b.y, b.z, b.w};
#pragma unroll
            for (int i = 0; i < 4; ++i)
#pragma unroll
                for (int j = 0; j < 4; ++j) acc[i][j] += av[i] * bv[j];
        }
        __syncthreads();
    }

#pragma unroll
    for (int i = 0; i < 4; ++i) {
        const int gm = bm + tm + i;
        if (gm < M) {
            float4 o;
            o.x = acc[i][0]; o.y = acc[i][1]; o.z = acc[i][2]; o.w = acc[i][3];
            if (RELU) {
                o.x = fmaxf(o.x, 0.f); o.y = fmaxf(o.y, 0.f);
                o.z = fmaxf(o.z, 0.f); o.w = fmaxf(o.w, 0.f);
            }
            *reinterpret_cast<float4*>(Cmat + (size_t)gm * C + bn + tn) = o;
        }
    }
}

// ---------------------------------------------------------------------------
// Pipeline (gather1 hoisted before GEMM1 -- linearity of the weighted sum):
//   tmp1 = gather_avg(x, seq)        [E,256]
//   edge = relu(tmp1 @ W1)           [E,256]
//   e1   = edge @ W2                 [E,256]  (written over tmp1's buffer)
//   out  = gather_avg(e1, useq)      [N,256]
// ws usage: 2 x E*256*4 = 51.2 MB
// ---------------------------------------------------------------------------
extern "C" void kernel_launch(void* const* d_in, const int* in_sizes, int n_in,
                              void* d_out, int out_size, void* d_ws, size_t ws_size,
                              hipStream_t stream) {
    const float* x   = (const float*)d_in[0];
    const int*   seq = (const int*)d_in[1];
    const int*   useq= (const int*)d_in[2];
    const float* W1  = (const float*)d_in[3];
    const float* W2  = (const float*)d_in[4];
    float* out = (float*)d_out;

    float* tmp1 = (float*)d_ws;                          // [E, C]
    float* edge = tmp1 + (size_t)N_EDGES * C;            // [E, C]

    gather_avg_kernel<<<dim3((N_EDGES + 3) / 4), dim3(256), 0, stream>>>(
        x, seq, tmp1, N_EDGES);

    dim3 ggrid((N_EDGES + 63) / 64, C / 64);
    gemm256_kernel<true><<<ggrid, dim3(256), 0, stream>>>(tmp1, W1, edge, N_EDGES);
    gemm256_kernel<false><<<ggrid, dim3(256), 0, stream>>>(edge, W2, tmp1, N_EDGES);

    gather_avg_kernel<<<dim3((N_NODES + 3) / 4), dim3(256), 0, stream>>>(
        tmp1, useq, out, N_NODES);
}

// Round 2
// 320.135 us; speedup vs baseline: 1.5193x; 1.5193x over previous
//
#include <hip/hip_runtime.h>

// Problem constants (match reference setup_inputs)
constexpr int N_NODES = 50000;
constexpr int N_EDGES = 25000;
constexpr int C = 256;   // IN == OUT == 256 channels
constexpr int L = 32;    // incidence list width

// Transposed bf16 weights live in device globals (keeps d_ws at exactly
// 51.2 MB = xb 25.6 + tmp1 12.8 + edge 12.8, which round-1 proved fits).
__device__ ushort W1T_g[C * C];   // [n][k] bf16
__device__ ushort W2T_g[C * C];   // [n][k] bf16

__device__ __forceinline__ float bf2f(unsigned int h) {
    union { unsigned int u; float f; } c; c.u = h << 16; return c.f;
}
__device__ __forceinline__ ushort f2bf(float f) {
    union { float f; unsigned int u; } c; c.f = f;
    unsigned int r = c.u + 0x7FFFu + ((c.u >> 16) & 1u);   // RNE
    return (ushort)(r >> 16);
}

// ---------------------------------------------------------------------------
// x [N,256] fp32 -> xb bf16. 4 elems/thread.
// ---------------------------------------------------------------------------
__global__ __launch_bounds__(256) void convert_x_kernel(
    const float* __restrict__ x, ushort* __restrict__ xb)
{
    const size_t i = ((size_t)blockIdx.x * 256 + threadIdx.x) * 4;
    const float4 v = *reinterpret_cast<const float4*>(x + i);
    ushort4 o;
    o.x = f2bf(v.x); o.y = f2bf(v.y); o.z = f2bf(v.z); o.w = f2bf(v.w);
    *reinterpret_cast<ushort4*>(xb + i) = o;
}

// ---------------------------------------------------------------------------
// W [256k,256n] fp32 row-major -> WT [n][k] bf16 (transposed), via LDS tile.
// grid (4,4,2): 64x64 tiles, z picks W1/W2.
// ---------------------------------------------------------------------------
__global__ __launch_bounds__(256) void wconv_kernel(
    const float* __restrict__ W1, const float* __restrict__ W2)
{
    const float* W  = blockIdx.z ? W2 : W1;
    ushort* WT      = blockIdx.z ? W2T_g : W1T_g;
    __shared__ float t[64][65];
    const int rr = threadIdx.x >> 6;    // 0..3
    const int cc = threadIdx.x & 63;    // 0..63
    const int br = blockIdx.x * 64;     // k tile
    const int bc = blockIdx.y * 64;     // n tile
#pragma unroll
    for (int i = 0; i < 16; ++i) {
        const int row = i * 4 + rr;
        t[row][cc] = W[(size_t)(br + row) * C + bc + cc];
    }
    __syncthreads();
#pragma unroll
    for (int i = 0; i < 16; ++i) {
        const int n = i * 4 + rr;
        WT[(size_t)(bc + n) * C + br + cc] = f2bf(t[cc][n]);
    }
}

// ---------------------------------------------------------------------------
// gather_avg: dst[row,:] = (1/cnt) * sum_{l: idx[row,l]>0} src_bf16[idx[row,l],:]
// Half-wave (32 lanes) per row, lane owns 8 channels (16B loads).
// Indices loaded one-per-lane and broadcast via __shfl width=32.
// ---------------------------------------------------------------------------
template <typename OutT>
__global__ __launch_bounds__(256) void gather_avg_kernel(
    const ushort* __restrict__ src, const int* __restrict__ idx,
    OutT* __restrict__ dst, int nrows)
{
    const int row = blockIdx.x * 8 + (threadIdx.x >> 5);
    const int ln  = threadIdx.x & 31;
    if (row >= nrows) return;

    const int myid = idx[(size_t)row * L + ln];
    const unsigned long long b = __ballot(myid > 0);
    const unsigned int halfmask = (unsigned int)(b >> (threadIdx.x & 32));
    const int cnt = __popc(halfmask);
    const bool all = (cnt == 0);
    const float w = all ? (1.0f / (float)L) : (1.0f / (float)cnt);

    float acc[8] = {0.f, 0.f, 0.f, 0.f, 0.f, 0.f, 0.f, 0.f};
#pragma unroll 4
    for (int l = 0; l < L; ++l) {
        const int id = __shfl(myid, l, 32);
        if (all || id > 0) {
            const uint4 v = *reinterpret_cast<const uint4*>(
                src + (size_t)id * C + ln * 8);
            acc[0] += bf2f(v.x & 0xFFFFu); acc[1] += bf2f(v.x >> 16);
            acc[2] += bf2f(v.y & 0xFFFFu); acc[3] += bf2f(v.y >> 16);
            acc[4] += bf2f(v.z & 0xFFFFu); acc[5] += bf2f(v.z >> 16);
            acc[6] += bf2f(v.w & 0xFFFFu); acc[7] += bf2f(v.w >> 16);
        }
    }

    if constexpr (sizeof(OutT) == 2) {
        ushort* d = (ushort*)dst + (size_t)row * C + ln * 8;
        ushort4 o0, o1;
        o0.x = f2bf(acc[0] * w); o0.y = f2bf(acc[1] * w);
        o0.z = f2bf(acc[2] * w); o0.w = f2bf(acc[3] * w);
        o1.x = f2bf(acc[4] * w); o1.y = f2bf(acc[5] * w);
        o1.z = f2bf(acc[6] * w); o1.w = f2bf(acc[7] * w);
        *reinterpret_cast<ushort4*>(d)     = o0;
        *reinterpret_cast<ushort4*>(d + 4) = o1;
    } else {
        float* d = (float*)dst + (size_t)row * C + ln * 8;
        float4 o0 = {acc[0] * w, acc[1] * w, acc[2] * w, acc[3] * w};
        float4 o1 = {acc[4] * w, acc[5] * w, acc[6] * w, acc[7] * w};
        *reinterpret_cast<float4*>(d)     = o0;
        *reinterpret_cast<float4*>(d + 4) = o1;
    }
}

// ---------------------------------------------------------------------------
// MFMA bf16 GEMM: C[M,256] = A[M,256] @ W, W given transposed bf16 [n][k].
// One wave = 16 rows x 256 cols (16 n-tiles of 16x16x32 mfma, 8 k-steps).
// A-frag: lane holds A[m=lane&15][k=quad*8+j] -> contiguous 16B load.
// B-frag: lane holds B[k=quad*8+j][n=lane&15] -> contiguous 16B from WT[n][k].
// C/D:    col=lane&15, row=quad*4+reg (m89-verified layout).
// ---------------------------------------------------------------------------
typedef __attribute__((ext_vector_type(8))) short bf16x8;
typedef __attribute__((ext_vector_type(4))) float f32x4;

template <bool RELU>
__global__ __launch_bounds__(256) void gemm_mfma_kernel(
    const ushort* __restrict__ A, int which_w,
    ushort* __restrict__ Cmat, int M)
{
    const ushort* __restrict__ BT = which_w ? W2T_g : W1T_g;
    const int wave = threadIdx.x >> 6;
    const int lane = threadIdx.x & 63;
    const int quad = lane >> 4;
    const int l16  = lane & 15;
    const int base = (blockIdx.x * 4 + wave) * 16;
    int mc = base + l16; if (mc > M - 1) mc = M - 1;   // clamp tail reads

    f32x4 acc[16];
    const f32x4 zero = {0.f, 0.f, 0.f, 0.f};
#pragma unroll
    for (int t = 0; t < 16; ++t) acc[t] = zero;

    const ushort* arow = A  + (size_t)mc  * C + quad * 8;
    const ushort* brow = BT + (size_t)l16 * C + quad * 8;

#pragma unroll
    for (int k0 = 0; k0 < C; k0 += 32) {
        const bf16x8 a = *reinterpret_cast<const bf16x8*>(arow + k0);
#pragma unroll
        for (int t = 0; t < 16; ++t) {
            const bf16x8 b = *reinterpret_cast<const bf16x8*>(
                brow + (size_t)t * 16 * C + k0);
            acc[t] = __builtin_amdgcn_mfma_f32_16x16x32_bf16(a, b, acc[t], 0, 0, 0);
        }
    }

#pragma unroll
    for (int t = 0; t < 16; ++t) {
#pragma unroll
        for (int r = 0; r < 4; ++r) {
            const int gm = base + quad * 4 + r;
            if (gm < M) {
                float v = acc[t][r];
                if (RELU) v = fmaxf(v, 0.f);
                Cmat[(size_t)gm * C + t * 16 + l16] = f2bf(v);
            }
        }
    }
}

// ---------------------------------------------------------------------------
// Pipeline (gather1 hoisted before GEMM1 -- linearity):
//   xb   = bf16(x)                       [N,256]
//   W1T/W2T = bf16(W^T)                  device globals
//   tmp1 = gather_avg(xb, seq)           [E,256] bf16
//   edge = relu(tmp1 @ W1)               [E,256] bf16
//   e1   = edge @ W2                     [E,256] bf16  (overwrites tmp1)
//   out  = gather_avg(e1, useq)          [N,256] fp32 -> d_out
// ws: xb 25.6MB + tmp1 12.8MB + edge 12.8MB = 51.2MB
// ---------------------------------------------------------------------------
extern "C" void kernel_launch(void* const* d_in, const int* in_sizes, int n_in,
                              void* d_out, int out_size, void* d_ws, size_t ws_size,
                              hipStream_t stream) {
    const float* x    = (const float*)d_in[0];
    const int*   seq  = (const int*)d_in[1];
    const int*   useq = (const int*)d_in[2];
    const float* W1   = (const float*)d_in[3];
    const float* W2   = (const float*)d_in[4];
    float* out = (float*)d_out;

    ushort* xb   = (ushort*)d_ws;                    // [N, C] bf16
    ushort* tmp1 = xb + (size_t)N_NODES * C;         // [E, C] bf16 (also e1)
    ushort* edge = tmp1 + (size_t)N_EDGES * C;       // [E, C] bf16

    convert_x_kernel<<<dim3((N_NODES * C) / (256 * 4)), dim3(256), 0, stream>>>(x, xb);
    wconv_kernel<<<dim3(4, 4, 2), dim3(256), 0, stream>>>(W1, W2);

    gather_avg_kernel<ushort><<<dim3(N_EDGES / 8), dim3(256), 0, stream>>>(
        xb, seq, tmp1, N_EDGES);

    const dim3 ggrid((N_EDGES + 63) / 64);
    gemm_mfma_kernel<true><<<ggrid, dim3(256), 0, stream>>>(tmp1, 0, edge, N_EDGES);
    gemm_mfma_kernel<false><<<ggrid, dim3(256), 0, stream>>>(edge, 1, tmp1, N_EDGES);

    gather_avg_kernel<float><<<dim3(N_NODES / 8), dim3(256), 0, stream>>>(
        tmp1, useq, out, N_NODES);
}

// Round 3
// 308.289 us; speedup vs baseline: 1.5777x; 1.0384x over previous
//
#include <hip/hip_runtime.h>

// Problem constants (match reference setup_inputs)
constexpr int N_NODES = 50000;
constexpr int N_EDGES = 25000;
constexpr int C = 256;   // IN == OUT == 256 channels
constexpr int L = 32;    // incidence list width

// Transposed bf16 weights in device globals (d_ws stays 51.2 MB for tables).
__device__ ushort W1T_g[C * C];   // [n][k] bf16
__device__ ushort W2T_g[C * C];   // [n][k] bf16

__device__ __forceinline__ float bf2f(unsigned int h) {
    union { unsigned int u; float f; } c; c.u = h << 16; return c.f;
}
__device__ __forceinline__ ushort f2bf(float f) {
    union { float f; unsigned int u; } c; c.f = f;
    unsigned int r = c.u + 0x7FFFu + ((c.u >> 16) & 1u);   // RNE
    return (ushort)(r >> 16);
}

// ---------------------------------------------------------------------------
// x [N,256] fp32 -> xb bf16. 4 elems/thread.
// ---------------------------------------------------------------------------
__global__ __launch_bounds__(256) void convert_x_kernel(
    const float* __restrict__ x, ushort* __restrict__ xb)
{
    const size_t i = ((size_t)blockIdx.x * 256 + threadIdx.x) * 4;
    const float4 v = *reinterpret_cast<const float4*>(x + i);
    ushort4 o;
    o.x = f2bf(v.x); o.y = f2bf(v.y); o.z = f2bf(v.z); o.w = f2bf(v.w);
    *reinterpret_cast<ushort4*>(xb + i) = o;
}

// ---------------------------------------------------------------------------
// W [256k,256n] fp32 row-major -> WT [n][k] bf16 (transposed), via LDS tile.
// ---------------------------------------------------------------------------
__global__ __launch_bounds__(256) void wconv_kernel(
    const float* __restrict__ W1, const float* __restrict__ W2)
{
    const float* W  = blockIdx.z ? W2 : W1;
    ushort* WT      = blockIdx.z ? W2T_g : W1T_g;
    __shared__ float t[64][65];
    const int rr = threadIdx.x >> 6;    // 0..3
    const int cc = threadIdx.x & 63;    // 0..63
    const int br = blockIdx.x * 64;     // k tile
    const int bc = blockIdx.y * 64;     // n tile
#pragma unroll
    for (int i = 0; i < 16; ++i) {
        const int row = i * 4 + rr;
        t[row][cc] = W[(size_t)(br + row) * C + bc + cc];
    }
    __syncthreads();
#pragma unroll
    for (int i = 0; i < 16; ++i) {
        const int n = i * 4 + rr;
        WT[(size_t)(bc + n) * C + br + cc] = f2bf(t[cc][n]);
    }
}

// ---------------------------------------------------------------------------
// Chunked gather_avg: dst[row, chunk*CH .. +CH] =
//     (1/cnt) * sum_{l: idx[row,l]>0} src_bf16[idx[row,l], chunk*CH .. +CH]
// Channel-chunked so each XCD's L2 holds one 3.2 MB table slice:
//   chunk = blockIdx.x & (NCHUNK-1)  -- with round-robin bid%8 -> XCD dispatch,
//   every XCD sees a FIXED chunk (8k mod NCHUNK == 0 for NCHUNK in {4,8}).
// Indices staged in LDS (padded [r][33] -> conflict-free broadcast reads).
// cnt==0 => all idx==0 => uniform avg of 32 copies of row 0 == row 0.
// ---------------------------------------------------------------------------
template <int CH, int NCHUNK, typename OutT>
__global__ __launch_bounds__(256) void gather_chunk_kernel(
    const ushort* __restrict__ src, const int* __restrict__ idx,
    OutT* __restrict__ dst, int nrows)
{
    constexpr int LPR = CH / 8;        // lanes per row (each lane: 8 ch, 16B)
    constexpr int RPB = 256 / LPR;     // rows per block
    const int chunk = blockIdx.x & (NCHUNK - 1);
    const int rb    = (int)(blockIdx.x / NCHUNK) * RPB;
    const int t     = threadIdx.x;

    __shared__ int sidx[RPB][33];
    constexpr int TOT = RPB * L;
#pragma unroll
    for (int i = 0; i < TOT / 256; ++i) {
        const int flat = i * 256 + t;
        const int r = flat >> 5, l = flat & 31;
        sidx[r][l] = (rb + r < nrows) ? idx[(size_t)(rb + r) * L + l] : 0;
    }
    __syncthreads();

    const int r   = t / LPR;
    const int ch  = chunk * CH + (t % LPR) * 8;   // this lane's 8 channels
    const int row = rb + r;

    float acc[8] = {0.f, 0.f, 0.f, 0.f, 0.f, 0.f, 0.f, 0.f};
    int cnt = 0;
#pragma unroll 4
    for (int l = 0; l < L; ++l) {
        const int id = sidx[r][l];
        if (id > 0) {
            ++cnt;
            const uint4 v = *reinterpret_cast<const uint4*>(
                src + (size_t)id * C + ch);
            acc[0] += bf2f(v.x & 0xFFFFu); acc[1] += bf2f(v.x >> 16);
            acc[2] += bf2f(v.y & 0xFFFFu); acc[3] += bf2f(v.y >> 16);
            acc[4] += bf2f(v.z & 0xFFFFu); acc[5] += bf2f(v.z >> 16);
            acc[6] += bf2f(v.w & 0xFFFFu); acc[7] += bf2f(v.w >> 16);
        }
    }
    if (row >= nrows) return;

    if (cnt == 0) {
        const uint4 v = *reinterpret_cast<const uint4*>(src + ch); // row 0
        if constexpr (sizeof(OutT) == 2) {
            *reinterpret_cast<uint4*>((ushort*)dst + (size_t)row * C + ch) = v;
        } else {
            float* d = (float*)dst + (size_t)row * C + ch;
            float4 o0 = {bf2f(v.x & 0xFFFFu), bf2f(v.x >> 16),
                         bf2f(v.y & 0xFFFFu), bf2f(v.y >> 16)};
            float4 o1 = {bf2f(v.z & 0xFFFFu), bf2f(v.z >> 16),
                         bf2f(v.w & 0xFFFFu), bf2f(v.w >> 16)};
            *reinterpret_cast<float4*>(d)     = o0;
            *reinterpret_cast<float4*>(d + 4) = o1;
        }
        return;
    }

    const float w = 1.0f / (float)cnt;
    if constexpr (sizeof(OutT) == 2) {
        uint4 o;
        o.x = (unsigned)f2bf(acc[0] * w) | ((unsigned)f2bf(acc[1] * w) << 16);
        o.y = (unsigned)f2bf(acc[2] * w) | ((unsigned)f2bf(acc[3] * w) << 16);
        o.z = (unsigned)f2bf(acc[4] * w) | ((unsigned)f2bf(acc[5] * w) << 16);
        o.w = (unsigned)f2bf(acc[6] * w) | ((unsigned)f2bf(acc[7] * w) << 16);
        *reinterpret_cast<uint4*>((ushort*)dst + (size_t)row * C + ch) = o;
    } else {
        float* d = (float*)dst + (size_t)row * C + ch;
        float4 o0 = {acc[0] * w, acc[1] * w, acc[2] * w, acc[3] * w};
        float4 o1 = {acc[4] * w, acc[5] * w, acc[6] * w, acc[7] * w};
        *reinterpret_cast<float4*>(d)     = o0;
        *reinterpret_cast<float4*>(d + 4) = o1;
    }
}

// ---------------------------------------------------------------------------
// MFMA bf16 GEMM: C[M,256] = A[M,256] @ W, W given transposed bf16 [n][k].
// One wave = 16 rows x 256 cols (16 n-tiles of 16x16x32 mfma, 8 k-steps).
// C/D: col=lane&15, row=quad*4+reg (m89-verified layout).
// ---------------------------------------------------------------------------
typedef __attribute__((ext_vector_type(8))) short bf16x8;
typedef __attribute__((ext_vector_type(4))) float f32x4;

template <bool RELU>
__global__ __launch_bounds__(256) void gemm_mfma_kernel(
    const ushort* __restrict__ A, int which_w,
    ushort* __restrict__ Cmat, int M)
{
    const ushort* __restrict__ BT = which_w ? W2T_g : W1T_g;
    const int wave = threadIdx.x >> 6;
    const int lane = threadIdx.x & 63;
    const int quad = lane >> 4;
    const int l16  = lane & 15;
    const int base = (blockIdx.x * 4 + wave) * 16;
    int mc = base + l16; if (mc > M - 1) mc = M - 1;   // clamp tail reads

    f32x4 acc[16];
    const f32x4 zero = {0.f, 0.f, 0.f, 0.f};
#pragma unroll
    for (int t = 0; t < 16; ++t) acc[t] = zero;

    const ushort* arow = A  + (size_t)mc  * C + quad * 8;
    const ushort* brow = BT + (size_t)l16 * C + quad * 8;

#pragma unroll
    for (int k0 = 0; k0 < C; k0 += 32) {
        const bf16x8 a = *reinterpret_cast<const bf16x8*>(arow + k0);
#pragma unroll
        for (int t = 0; t < 16; ++t) {
            const bf16x8 b = *reinterpret_cast<const bf16x8*>(
                brow + (size_t)t * 16 * C + k0);
            acc[t] = __builtin_amdgcn_mfma_f32_16x16x32_bf16(a, b, acc[t], 0, 0, 0);
        }
    }

#pragma unroll
    for (int t = 0; t < 16; ++t) {
#pragma unroll
        for (int r = 0; r < 4; ++r) {
            const int gm = base + quad * 4 + r;
            if (gm < M) {
                float v = acc[t][r];
                if (RELU) v = fmaxf(v, 0.f);
                Cmat[(size_t)gm * C + t * 16 + l16] = f2bf(v);
            }
        }
    }
}

// ---------------------------------------------------------------------------
// Pipeline (gather1 hoisted before GEMM1 -- linearity):
//   xb   = bf16(x)                       [N,256]
//   tmp1 = gather_avg(xb, seq)           [E,256] bf16   (chunked, 8x32ch)
//   edge = relu(tmp1 @ W1)               [E,256] bf16
//   e1   = edge @ W2                     [E,256] bf16   (overwrites tmp1)
//   out  = gather_avg(e1, useq)          [N,256] fp32   (chunked, 4x64ch)
// ws: xb 25.6MB + tmp1 12.8MB + edge 12.8MB = 51.2MB
// ---------------------------------------------------------------------------
extern "C" void kernel_launch(void* const* d_in, const int* in_sizes, int n_in,
                              void* d_out, int out_size, void* d_ws, size_t ws_size,
                              hipStream_t stream) {
    const float* x    = (const float*)d_in[0];
    const int*   seq  = (const int*)d_in[1];
    const int*   useq = (const int*)d_in[2];
    const float* W1   = (const float*)d_in[3];
    const float* W2   = (const float*)d_in[4];
    float* out = (float*)d_out;

    ushort* xb   = (ushort*)d_ws;                    // [N, C] bf16
    ushort* tmp1 = xb + (size_t)N_NODES * C;         // [E, C] bf16 (also e1)
    ushort* edge = tmp1 + (size_t)N_EDGES * C;       // [E, C] bf16

    convert_x_kernel<<<dim3((N_NODES * C) / (256 * 4)), dim3(256), 0, stream>>>(x, xb);
    wconv_kernel<<<dim3(4, 4, 2), dim3(256), 0, stream>>>(W1, W2);

    // gather1: table xb 25.6MB -> 8 chunks x 32ch (3.2MB slice per XCD)
    const int rblk1 = (N_EDGES + 63) / 64;
    gather_chunk_kernel<32, 8, ushort><<<dim3(8 * rblk1), dim3(256), 0, stream>>>(
        xb, seq, tmp1, N_EDGES);

    const dim3 ggrid((N_EDGES + 63) / 64);
    gemm_mfma_kernel<true><<<ggrid, dim3(256), 0, stream>>>(tmp1, 0, edge, N_EDGES);
    gemm_mfma_kernel<false><<<ggrid, dim3(256), 0, stream>>>(edge, 1, tmp1, N_EDGES);

    // gather2: table e1 12.8MB -> 4 chunks x 64ch (3.2MB slice per XCD pair)
    const int rblk2 = (N_NODES + 31) / 32;
    gather_chunk_kernel<64, 4, float><<<dim3(4 * rblk2), dim3(256), 0, stream>>>(
        tmp1, useq, out, N_NODES);
}

// Round 4
// 280.500 us; speedup vs baseline: 1.7339x; 1.0991x over previous
//
#include <hip/hip_runtime.h>

// Problem constants (match reference setup_inputs)
constexpr int N_NODES = 50000;
constexpr int N_EDGES = 25000;
constexpr int C = 256;   // IN == OUT == 256 channels
constexpr int L = 32;    // incidence list width

// Transposed bf16 weights in device globals.
__device__ ushort W1T_g[C * C];   // [n][k] bf16
__device__ ushort W2T_g[C * C];   // [n][k] bf16

__device__ __forceinline__ ushort f2bf(float f) {
    union { float f; unsigned int u; } c; c.f = f;
    unsigned int r = c.u + 0x7FFFu + ((c.u >> 16) & 1u);   // RNE
    return (ushort)(r >> 16);
}
// bf16 pair unpack: low half = shift, high half = mask (1 VALU op each)
__device__ __forceinline__ float bflo(unsigned int u) {
    union { unsigned int x; float f; } c; c.x = u << 16; return c.f;
}
__device__ __forceinline__ float bfhi(unsigned int u) {
    union { unsigned int x; float f; } c; c.x = u & 0xFFFF0000u; return c.f;
}
__device__ __forceinline__ void acc_uint4(float* acc, const uint4 v) {
    acc[0] += bflo(v.x); acc[1] += bfhi(v.x);
    acc[2] += bflo(v.y); acc[3] += bfhi(v.y);
    acc[4] += bflo(v.z); acc[5] += bfhi(v.z);
    acc[6] += bflo(v.w); acc[7] += bfhi(v.w);
}

// ---------------------------------------------------------------------------
// x [N,256] fp32 -> xb bf16. 4 elems/thread.
// ---------------------------------------------------------------------------
__global__ __launch_bounds__(256) void convert_x_kernel(
    const float* __restrict__ x, ushort* __restrict__ xb)
{
    const size_t i = ((size_t)blockIdx.x * 256 + threadIdx.x) * 4;
    const float4 v = *reinterpret_cast<const float4*>(x + i);
    ushort4 o;
    o.x = f2bf(v.x); o.y = f2bf(v.y); o.z = f2bf(v.z); o.w = f2bf(v.w);
    *reinterpret_cast<ushort4*>(xb + i) = o;
}

// ---------------------------------------------------------------------------
// W [256k,256n] fp32 row-major -> WT [n][k] bf16 (transposed), via LDS tile.
// ---------------------------------------------------------------------------
__global__ __launch_bounds__(256) void wconv_kernel(
    const float* __restrict__ W1, const float* __restrict__ W2)
{
    const float* W  = blockIdx.z ? W2 : W1;
    ushort* WT      = blockIdx.z ? W2T_g : W1T_g;
    __shared__ float t[64][65];
    const int rr = threadIdx.x >> 6;    // 0..3
    const int cc = threadIdx.x & 63;    // 0..63
    const int br = blockIdx.x * 64;     // k tile
    const int bc = blockIdx.y * 64;     // n tile
#pragma unroll
    for (int i = 0; i < 16; ++i) {
        const int row = i * 4 + rr;
        t[row][cc] = W[(size_t)(br + row) * C + bc + cc];
    }
    __syncthreads();
#pragma unroll
    for (int i = 0; i < 16; ++i) {
        const int n = i * 4 + rr;
        WT[(size_t)(bc + n) * C + br + cc] = f2bf(t[cc][n]);
    }
}

// ---------------------------------------------------------------------------
// gather_edge (gather1): tmp1[row,:] = avg over valid slots of xb[seq[row,:],:]
// Unchunked: half-wave per row, 512B/row granule (R3 showed 64B granule
// regresses). BRANCHLESS: always load (id==0 reads row 0 -- valid), then
// subtract the (L-cnt) spurious row-0 contributions.
//   cnt>0 : out = (acc - (L-cnt)*x0) / cnt
//   cnt==0: out = acc / L            (== row 0 exactly, matches uniform avg)
// ---------------------------------------------------------------------------
__global__ __launch_bounds__(256) void gather_edge_kernel(
    const ushort* __restrict__ src, const int* __restrict__ idx,
    ushort* __restrict__ dst, int nrows)
{
    const int row = blockIdx.x * 8 + (threadIdx.x >> 5);
    const int ln  = threadIdx.x & 31;
    if (row >= nrows) return;

    const int myid = idx[(size_t)row * L + ln];
    const unsigned long long b = __ballot(myid > 0);
    const unsigned int halfmask = (unsigned int)(b >> (threadIdx.x & 32));
    const int cnt = __popc(halfmask);

    float acc[8] = {0.f, 0.f, 0.f, 0.f, 0.f, 0.f, 0.f, 0.f};
#pragma unroll
    for (int l = 0; l < L; ++l) {
        const int id = __shfl(myid, l, 32);
        const uint4 v = *reinterpret_cast<const uint4*>(
            src + (size_t)id * C + ln * 8);
        acc_uint4(acc, v);
    }
    const uint4 v0 = *reinterpret_cast<const uint4*>(src + ln * 8); // row 0
    float x0[8];
    x0[0] = bflo(v0.x); x0[1] = bfhi(v0.x); x0[2] = bflo(v0.y); x0[3] = bfhi(v0.y);
    x0[4] = bflo(v0.z); x0[5] = bfhi(v0.z); x0[6] = bflo(v0.w); x0[7] = bfhi(v0.w);

    const float corr = (cnt == 0) ? 0.f : (float)(L - cnt);
    const float inv  = (cnt == 0) ? (1.f / (float)L) : (1.f / (float)cnt);

    ushort* d = dst + (size_t)row * C + ln * 8;
    uint4 o;
    o.x = (unsigned)f2bf((acc[0] - corr * x0[0]) * inv) |
          ((unsigned)f2bf((acc[1] - corr * x0[1]) * inv) << 16);
    o.y = (unsigned)f2bf((acc[2] - corr * x0[2]) * inv) |
          ((unsigned)f2bf((acc[3] - corr * x0[3]) * inv) << 16);
    o.z = (unsigned)f2bf((acc[4] - corr * x0[4]) * inv) |
          ((unsigned)f2bf((acc[5] - corr * x0[5]) * inv) << 16);
    o.w = (unsigned)f2bf((acc[6] - corr * x0[6]) * inv) |
          ((unsigned)f2bf((acc[7] - corr * x0[7]) * inv) << 16);
    *reinterpret_cast<uint4*>(d) = o;
}

// ---------------------------------------------------------------------------
// gather_node (gather2): out[row, chunk*64 .. +64] fp32.
// Keeps the R3 win: 4 channel-chunks x 64ch (128B/row granule, 3.2MB slice).
// Branchless like gather_edge. Indices staged in LDS.
// ---------------------------------------------------------------------------
__global__ __launch_bounds__(256) void gather_node_kernel(
    const ushort* __restrict__ src, const int* __restrict__ idx,
    float* __restrict__ dst, int nrows)
{
    constexpr int CH = 64, NCHUNK = 4;
    constexpr int LPR = CH / 8;        // 8 lanes per row
    constexpr int RPB = 256 / LPR;     // 32 rows per block
    const int chunk = blockIdx.x & (NCHUNK - 1);
    const int rb    = (int)(blockIdx.x / NCHUNK) * RPB;
    const int t     = threadIdx.x;

    __shared__ int sidx[RPB][33];
#pragma unroll
    for (int i = 0; i < (RPB * L) / 256; ++i) {
        const int flat = i * 256 + t;
        const int r = flat >> 5, l = flat & 31;
        sidx[r][l] = (rb + r < nrows) ? idx[(size_t)(rb + r) * L + l] : 0;
    }
    __syncthreads();

    const int r   = t / LPR;
    const int ch  = chunk * CH + (t % LPR) * 8;
    const int row = rb + r;
    if (row >= nrows) return;

    float acc[8] = {0.f, 0.f, 0.f, 0.f, 0.f, 0.f, 0.f, 0.f};
    int cnt = 0;
#pragma unroll
    for (int l = 0; l < L; ++l) {
        const int id = sidx[r][l];
        cnt += (id > 0) ? 1 : 0;
        const uint4 v = *reinterpret_cast<const uint4*>(
            src + (size_t)id * C + ch);
        acc_uint4(acc, v);
    }
    const uint4 v0 = *reinterpret_cast<const uint4*>(src + ch);  // row 0
    float x0[8];
    x0[0] = bflo(v0.x); x0[1] = bfhi(v0.x); x0[2] = bflo(v0.y); x0[3] = bfhi(v0.y);
    x0[4] = bflo(v0.z); x0[5] = bfhi(v0.z); x0[6] = bflo(v0.w); x0[7] = bfhi(v0.w);

    const float corr = (cnt == 0) ? 0.f : (float)(L - cnt);
    const float inv  = (cnt == 0) ? (1.f / (float)L) : (1.f / (float)cnt);

    float* d = dst + (size_t)row * C + ch;
    float4 o0 = {(acc[0] - corr * x0[0]) * inv, (acc[1] - corr * x0[1]) * inv,
                 (acc[2] - corr * x0[2]) * inv, (acc[3] - corr * x0[3]) * inv};
    float4 o1 = {(acc[4] - corr * x0[4]) * inv, (acc[5] - corr * x0[5]) * inv,
                 (acc[6] - corr * x0[6]) * inv, (acc[7] - corr * x0[7]) * inv};
    *reinterpret_cast<float4*>(d)     = o0;
    *reinterpret_cast<float4*>(d + 4) = o1;
}

// ---------------------------------------------------------------------------
// MFMA bf16 GEMM: C[M,256] = A[M,256] @ W, W transposed bf16 [n][k].
// Wave tile: 32 rows x 128 cols (2x8 mfma 16x16x32 tiles, B reused across
// the two row-halves -> half the per-wave B traffic of the 16x256 shape).
// grid: (ceil(M/128), 2); blockIdx.y picks the n-half.
// C/D: col=lane&15, row=quad*4+reg (m89-verified layout).
// ---------------------------------------------------------------------------
typedef __attribute__((ext_vector_type(8))) short bf16x8;
typedef __attribute__((ext_vector_type(4))) float f32x4;

template <bool RELU>
__global__ __launch_bounds__(256) void gemm_mfma_kernel(
    const ushort* __restrict__ A, int which_w,
    ushort* __restrict__ Cmat, int M)
{
    const ushort* __restrict__ BT = which_w ? W2T_g : W1T_g;
    const int wave  = threadIdx.x >> 6;
    const int lane  = threadIdx.x & 63;
    const int quad  = lane >> 4;
    const int l16   = lane & 15;
    const int base  = (blockIdx.x * 4 + wave) * 32;
    const int nbase = blockIdx.y * 128;

    int m0 = base + l16;      if (m0 > M - 1) m0 = M - 1;
    int m1 = base + 16 + l16; if (m1 > M - 1) m1 = M - 1;

    f32x4 acc[2][8];
    const f32x4 zero = {0.f, 0.f, 0.f, 0.f};
#pragma unroll
    for (int p = 0; p < 2; ++p)
#pragma unroll
        for (int t = 0; t < 8; ++t) acc[p][t] = zero;

    const ushort* a0 = A + (size_t)m0 * C + quad * 8;
    const ushort* a1 = A + (size_t)m1 * C + quad * 8;
    const ushort* br = BT + (size_t)(nbase + l16) * C + quad * 8;

#pragma unroll
    for (int k0 = 0; k0 < C; k0 += 32) {
        const bf16x8 av0 = *reinterpret_cast<const bf16x8*>(a0 + k0);
        const bf16x8 av1 = *reinterpret_cast<const bf16x8*>(a1 + k0);
#pragma unroll
        for (int t = 0; t < 8; ++t) {
            const bf16x8 b = *reinterpret_cast<const bf16x8*>(
                br + (size_t)t * 16 * C + k0);
            acc[0][t] = __builtin_amdgcn_mfma_f32_16x16x32_bf16(av0, b, acc[0][t], 0, 0, 0);
            acc[1][t] = __builtin_amdgcn_mfma_f32_16x16x32_bf16(av1, b, acc[1][t], 0, 0, 0);
        }
    }

#pragma unroll
    for (int p = 0; p < 2; ++p)
#pragma unroll
    for (int t = 0; t < 8; ++t)
#pragma unroll
    for (int r = 0; r < 4; ++r) {
        const int gm = base + p * 16 + quad * 4 + r;
        if (gm < M) {
            float v = acc[p][t][r];
            if (RELU) v = fmaxf(v, 0.f);
            Cmat[(size_t)gm * C + nbase + t * 16 + l16] = f2bf(v);
        }
    }
}

// ---------------------------------------------------------------------------
// Pipeline (gather1 hoisted before GEMM1 -- linearity):
//   xb   = bf16(x)                       [N,256]
//   tmp1 = gather_edge(xb, seq)          [E,256] bf16  (unchunked, 512B/row)
//   edge = relu(tmp1 @ W1)               [E,256] bf16
//   e1   = edge @ W2                     [E,256] bf16  (overwrites tmp1)
//   out  = gather_node(e1, useq)         [N,256] fp32  (4x64ch chunks)
// ws: xb 25.6MB + tmp1 12.8MB + edge 12.8MB = 51.2MB
// ---------------------------------------------------------------------------
extern "C" void kernel_launch(void* const* d_in, const int* in_sizes, int n_in,
                              void* d_out, int out_size, void* d_ws, size_t ws_size,
                              hipStream_t stream) {
    const float* x    = (const float*)d_in[0];
    const int*   seq  = (const int*)d_in[1];
    const int*   useq = (const int*)d_in[2];
    const float* W1   = (const float*)d_in[3];
    const float* W2   = (const float*)d_in[4];
    float* out = (float*)d_out;

    ushort* xb   = (ushort*)d_ws;                    // [N, C] bf16
    ushort* tmp1 = xb + (size_t)N_NODES * C;         // [E, C] bf16 (also e1)
    ushort* edge = tmp1 + (size_t)N_EDGES * C;       // [E, C] bf16

    convert_x_kernel<<<dim3((N_NODES * C) / (256 * 4)), dim3(256), 0, stream>>>(x, xb);
    wconv_kernel<<<dim3(4, 4, 2), dim3(256), 0, stream>>>(W1, W2);

    gather_edge_kernel<<<dim3((N_EDGES + 7) / 8), dim3(256), 0, stream>>>(
        xb, seq, tmp1, N_EDGES);

    const dim3 ggrid((N_EDGES + 127) / 128, 2);
    gemm_mfma_kernel<true><<<ggrid, dim3(256), 0, stream>>>(tmp1, 0, edge, N_EDGES);
    gemm_mfma_kernel<false><<<ggrid, dim3(256), 0, stream>>>(edge, 1, tmp1, N_EDGES);

    const int rblk2 = (N_NODES + 31) / 32;
    gather_node_kernel<<<dim3(4 * rblk2), dim3(256), 0, stream>>>(
        tmp1, useq, out, N_NODES);
}